// Round 1
// baseline (460.362 us; speedup 1.0000x reference)
//
#include <hip/hip_runtime.h>
#include <hip/hip_bf16.h>
#include <stdint.h>

typedef float  f32x4 __attribute__((ext_vector_type(4)));
typedef short  s16x8 __attribute__((ext_vector_type(8)));

#define D_MODEL 2048
#define NHEADS  16
#define DK      128
#define BATCH   2
#define SEQ     2048
#define MROWS   (BATCH*SEQ)   // 4096

__device__ __forceinline__ unsigned short f2bf(float f) {
  union { float f; unsigned int u; } v; v.f = f;
  unsigned int r = v.u + 0x7FFFu + ((v.u >> 16) & 1u);
  return (unsigned short)(r >> 16);
}

__device__ __forceinline__ void async16(const void* g, void* l) {
  __builtin_amdgcn_global_load_lds(
      (const __attribute__((address_space(1))) unsigned int*)g,
      (__attribute__((address_space(3))) unsigned int*)l,
      16, 0, 0);
}

// ---------------- fp32 -> bf16 convert (8 elems/thread) ----------------
__global__ __launch_bounds__(256) void f2b_kernel(const float* __restrict__ s,
                                                  unsigned short* __restrict__ d,
                                                  int n8) {
  int i = blockIdx.x * 256 + threadIdx.x;
  if (i >= n8) return;
  const float4* s4 = (const float4*)s;
  float4 a = s4[2*i];
  float4 b = s4[2*i+1];
  s16x8 o;
  o[0] = (short)f2bf(a.x); o[1] = (short)f2bf(a.y);
  o[2] = (short)f2bf(a.z); o[3] = (short)f2bf(a.w);
  o[4] = (short)f2bf(b.x); o[5] = (short)f2bf(b.y);
  o[6] = (short)f2bf(b.z); o[7] = (short)f2bf(b.w);
  *(s16x8*)(d + 8*(size_t)i) = o;
}

// ---------------- weight transpose + convert: Wt[n][k] = bf16(W[k][n]) ----------------
__global__ __launch_bounds__(256) void wtrans_kernel(const float* __restrict__ Wq,
                                                     const float* __restrict__ Wk,
                                                     const float* __restrict__ Wv,
                                                     const float* __restrict__ Wo,
                                                     unsigned short* __restrict__ WqT,
                                                     unsigned short* __restrict__ WkT,
                                                     unsigned short* __restrict__ WvT,
                                                     unsigned short* __restrict__ WoT) {
  const float* W; unsigned short* Wt;
  switch (blockIdx.z) {
    case 0:  W = Wq; Wt = WqT; break;
    case 1:  W = Wk; Wt = WkT; break;
    case 2:  W = Wv; Wt = WvT; break;
    default: W = Wo; Wt = WoT; break;
  }
  __shared__ float tl[32][33];
  int x = threadIdx.x, y = threadIdx.y;
  int n0 = blockIdx.x * 32, k0 = blockIdx.y * 32;
  #pragma unroll
  for (int j = 0; j < 32; j += 8)
    tl[y + j][x] = W[(size_t)(k0 + y + j) * D_MODEL + n0 + x];
  __syncthreads();
  #pragma unroll
  for (int j = 0; j < 32; j += 8)
    Wt[(size_t)(n0 + y + j) * D_MODEL + k0 + x] = f2bf(tl[x][y + j]);
}

// ---------------- GEMM: C[m][n] = sum_k A[m][k]*Bt[n][k] + bias[n]  (m97 structure) ----------------
// mode 0: fp32 plain [M][N] out.  mode 1: bf16 head-split out [B,H,S,dk], (acc+bias)*scale.
__global__ __launch_bounds__(256) void gemm_bt(const unsigned short* __restrict__ A,
                                               const unsigned short* __restrict__ Bt,
                                               const float* __restrict__ bias,
                                               void* __restrict__ Cout,
                                               int M, int N, int K,
                                               int mode, float scale) {
  __shared__ unsigned short As[128*32];
  __shared__ unsigned short Bs[128*32];
  const int t  = threadIdx.x;
  const int l  = t & 63, w = t >> 6;
  const int wr = w >> 1, wc = w & 1;
  const int m0 = blockIdx.y * 128, n0 = blockIdx.x * 128;
  const int lr = l & 15, lg = l >> 4;

  f32x4 acc[4][4] = {};

  for (int k0 = 0; k0 < K; k0 += 32) {
    __syncthreads();
    #pragma unroll
    for (int i = 0; i < 2; ++i) {
      int c    = t + 256*i;           // 512 chunks of 16B per tile
      int row  = c >> 2;
      int col8 = (c & 3) * 8;
      async16(A  + (size_t)(m0 + row)*K + k0 + col8, (char*)As + c*16);
      async16(Bt + (size_t)(n0 + row)*K + k0 + col8, (char*)Bs + c*16);
    }
    asm volatile("s_waitcnt vmcnt(0)" ::: "memory");
    __syncthreads();

    s16x8 af[4], bfr[4];
    #pragma unroll
    for (int m = 0; m < 4; ++m)
      af[m] = *(const s16x8*)&As[(wr*64 + m*16 + lr)*32 + 8*lg];
    #pragma unroll
    for (int n = 0; n < 4; ++n)
      bfr[n] = *(const s16x8*)&Bs[(wc*64 + n*16 + lr)*32 + 8*lg];
    #pragma unroll
    for (int m = 0; m < 4; ++m)
      #pragma unroll
      for (int n = 0; n < 4; ++n)
        acc[m][n] = __builtin_amdgcn_mfma_f32_16x16x32_bf16(af[m], bfr[n], acc[m][n], 0, 0, 0);
  }

  if (mode == 0) {
    float* C = (float*)Cout;
    #pragma unroll
    for (int n = 0; n < 4; ++n) {
      int col = n0 + wc*64 + n*16 + lr;
      float bv = bias[col];
      #pragma unroll
      for (int m = 0; m < 4; ++m) {
        int rowb = m0 + wr*64 + m*16 + lg*4;
        #pragma unroll
        for (int r = 0; r < 4; ++r)
          C[(size_t)(rowb + r)*N + col] = (acc[m][n][r] + bv) * scale;
      }
    }
  } else {
    unsigned short* C = (unsigned short*)Cout;
    #pragma unroll
    for (int n = 0; n < 4; ++n) {
      int col = n0 + wc*64 + n*16 + lr;
      float bv = bias[col];
      int h = col >> 7, dkk = col & 127;
      #pragma unroll
      for (int m = 0; m < 4; ++m) {
        int rowb = m0 + wr*64 + m*16 + lg*4;
        #pragma unroll
        for (int r = 0; r < 4; ++r) {
          int row = rowb + r;
          int b = row >> 11, s = row & 2047;
          C[((size_t)((b*NHEADS + h)*SEQ + s))*DK + dkk] = f2bf((acc[m][n][r] + bv) * scale);
        }
      }
    }
  }
}

// ---------------- flash attention: Q,K,V bf16 [B,H,S,dk] -> O bf16 [B*S, D] ----------------
__global__ __launch_bounds__(256) void attn_kernel(const unsigned short* __restrict__ Q,
                                                   const unsigned short* __restrict__ K,
                                                   const unsigned short* __restrict__ V,
                                                   unsigned short* __restrict__ O) {
  __shared__ unsigned short Kl[64*128];     // swizzled storage (row*256B, byte ^ ((row&7)<<4))
  __shared__ unsigned short Vt[128*72];     // transposed [dv][kv], padded rows (72)
  __shared__ unsigned short Pl[4][16*72];   // per-wave P tile, padded

  const int t  = threadIdx.x;
  const int l  = t & 63, w = t >> 6;
  const int lr = l & 15, lg = l >> 4;
  const int bh = blockIdx.y;
  const int b  = bh >> 4, h = bh & 15;
  const int q0 = blockIdx.x * 64;

  const unsigned short* Qp = Q + (size_t)bh * SEQ * DK;
  const unsigned short* Kp = K + (size_t)bh * SEQ * DK;
  const unsigned short* Vp = V + (size_t)bh * SEQ * DK;

  // Q fragments (16 rows per wave), scale 1/sqrt(dk) already folded into Q
  s16x8 aq[4];
  #pragma unroll
  for (int kk = 0; kk < 4; ++kk)
    aq[kk] = *(const s16x8*)(Qp + (size_t)(q0 + w*16 + lr)*DK + kk*32 + 8*lg);

  f32x4 acc[8] = {};
  float Mr[4] = {-INFINITY, -INFINITY, -INFINITY, -INFINITY};
  float Lr[4] = {0.f, 0.f, 0.f, 0.f};

  const int vp_ = t & 31;          // kv pair id
  const int vd0 = (t >> 5) * 8;    // dv base (0..56)

  for (int kv0 = 0; kv0 < SEQ; kv0 += 64) {
    __syncthreads();
    // stage K (swizzled source, linear LDS dest)
    #pragma unroll
    for (int i = 0; i < 4; ++i) {
      int c   = t + 256*i;                 // 1024 chunks of 16B
      int row = c >> 4;
      int ob  = (c & 15) << 4;
      int sb  = ob ^ ((row & 7) << 4);
      async16((const char*)(Kp + (size_t)(kv0 + row)*DK) + sb, (char*)Kl + c*16);
    }
    // stage V transposed into Vt[dv][kv] (pairs of kv packed as b32 writes)
    #pragma unroll
    for (int rep = 0; rep < 2; ++rep) {
      int dvb = vd0 + rep*64;
      s16x8 va = *(const s16x8*)(Vp + (size_t)(kv0 + 2*vp_    )*DK + dvb);
      s16x8 vb = *(const s16x8*)(Vp + (size_t)(kv0 + 2*vp_ + 1)*DK + dvb);
      #pragma unroll
      for (int j = 0; j < 8; ++j) {
        unsigned int pk = (unsigned int)(unsigned short)va[j]
                        | ((unsigned int)(unsigned short)vb[j] << 16);
        *(unsigned int*)&Vt[(dvb + j)*72 + 2*vp_] = pk;
      }
    }
    asm volatile("s_waitcnt vmcnt(0) lgkmcnt(0)" ::: "memory");
    __syncthreads();

    // S = Q K^T  (C-layout: row=(lg*4+r), col=lr+16n)
    f32x4 sc[4] = {};
    #pragma unroll
    for (int n = 0; n < 4; ++n) {
      #pragma unroll
      for (int kk = 0; kk < 4; ++kk) {
        int krow = n*16 + lr;
        int dkb  = (kk*32 + 8*lg) * 2;
        int off  = krow*256 + (dkb ^ ((krow & 7) << 4));
        s16x8 bk = *(const s16x8*)((const char*)Kl + off);
        sc[n] = __builtin_amdgcn_mfma_f32_16x16x32_bf16(aq[kk], bk, sc[n], 0, 0, 0);
      }
    }

    // online softmax (rows spread over 16-lane groups)
    #pragma unroll
    for (int r = 0; r < 4; ++r) {
      float mloc = fmaxf(fmaxf(sc[0][r], sc[1][r]), fmaxf(sc[2][r], sc[3][r]));
      #pragma unroll
      for (int off = 1; off < 16; off <<= 1)
        mloc = fmaxf(mloc, __shfl_xor(mloc, off, 64));
      float mnew = fmaxf(Mr[r], mloc);
      float corr = __expf(Mr[r] - mnew);
      Mr[r] = mnew;
      float rs = 0.f;
      #pragma unroll
      for (int n = 0; n < 4; ++n) {
        float p = __expf(sc[n][r] - mnew);
        sc[n][r] = p;
        rs += p;
      }
      #pragma unroll
      for (int off = 1; off < 16; off <<= 1)
        rs += __shfl_xor(rs, off, 64);
      Lr[r] = Lr[r]*corr + rs;
      #pragma unroll
      for (int n = 0; n < 8; ++n) acc[n][r] *= corr;
    }

    // write P (bf16) to per-wave LDS, then read back as A-fragments
    #pragma unroll
    for (int r = 0; r < 4; ++r)
      #pragma unroll
      for (int n = 0; n < 4; ++n)
        Pl[w][(lg*4 + r)*72 + n*16 + lr] = f2bf(sc[n][r]);
    asm volatile("s_waitcnt lgkmcnt(0)" ::: "memory");

    s16x8 ap[2];
    #pragma unroll
    for (int kk = 0; kk < 2; ++kk)
      ap[kk] = *(const s16x8*)&Pl[w][lr*72 + kk*32 + 8*lg];

    // O += P V
    #pragma unroll
    for (int n = 0; n < 8; ++n) {
      #pragma unroll
      for (int kk = 0; kk < 2; ++kk) {
        s16x8 bv = *(const s16x8*)&Vt[(n*16 + lr)*72 + kk*32 + 8*lg];
        acc[n] = __builtin_amdgcn_mfma_f32_16x16x32_bf16(ap[kk], bv, acc[n], 0, 0, 0);
      }
    }
  }

  // epilogue: O[b*S+s][h*128+dv] = acc/L
  int srow = q0 + w*16 + lg*4;
  #pragma unroll
  for (int r = 0; r < 4; ++r) {
    float inv = 1.0f / Lr[r];
    size_t base = ((size_t)(b*SEQ + srow + r)) * D_MODEL + h*DK;
    #pragma unroll
    for (int n = 0; n < 8; ++n)
      O[base + n*16 + lr] = f2bf(acc[n][r] * inv);
  }
}

extern "C" void kernel_launch(void* const* d_in, const int* in_sizes, int n_in,
                              void* d_out, int out_size, void* d_ws, size_t ws_size,
                              hipStream_t stream) {
  const float* q  = (const float*)d_in[0];
  const float* k  = (const float*)d_in[1];
  const float* v  = (const float*)d_in[2];
  const float* Wq = (const float*)d_in[3];
  const float* bq = (const float*)d_in[4];
  const float* Wk = (const float*)d_in[5];
  const float* bk = (const float*)d_in[6];
  const float* Wv = (const float*)d_in[7];
  const float* bv = (const float*)d_in[8];
  const float* Wo = (const float*)d_in[9];
  const float* bo = (const float*)d_in[10];
  float* out = (float*)d_out;

  char* ws = (char*)d_ws;
  const size_t SZT = (size_t)MROWS * D_MODEL * 2;     // 16.78 MB (bf16 activation tensor)
  const size_t SZW = (size_t)D_MODEL * D_MODEL * 2;   //  8.39 MB (bf16 weight)

  unsigned short* qb  = (unsigned short*)(ws);
  unsigned short* kb  = (unsigned short*)(ws + SZT);
  unsigned short* vb  = (unsigned short*)(ws + 2*SZT);
  unsigned short* WqT = (unsigned short*)(ws + 3*SZT);
  unsigned short* WkT = (unsigned short*)(ws + 3*SZT + SZW);
  unsigned short* WvT = (unsigned short*)(ws + 3*SZT + 2*SZW);
  unsigned short* WoT = (unsigned short*)(ws + 3*SZT + 3*SZW);
  unsigned short* Qh  = (unsigned short*)(ws + 3*SZT + 4*SZW);
  unsigned short* Kh  = (unsigned short*)(ws + 4*SZT + 4*SZW);
  unsigned short* Vh  = (unsigned short*)(ws + 5*SZT + 4*SZW);
  unsigned short* Oc  = qb;   // qb is dead after the Q projection; reuse for attention output

  const int n8 = MROWS * D_MODEL / 8;  // 1,048,576 threads
  f2b_kernel<<<n8/256, 256, 0, stream>>>(q, qb, n8);
  f2b_kernel<<<n8/256, 256, 0, stream>>>(k, kb, n8);
  f2b_kernel<<<n8/256, 256, 0, stream>>>(v, vb, n8);
  wtrans_kernel<<<dim3(64, 64, 4), dim3(32, 8), 0, stream>>>(Wq, Wk, Wv, Wo, WqT, WkT, WvT, WoT);

  const float qscale = 0.08838834764831845f;  // 1/sqrt(128), folded into Q (incl. bias)
  gemm_bt<<<dim3(16, 32), 256, 0, stream>>>(qb, WqT, bq, Qh, MROWS, D_MODEL, D_MODEL, 1, qscale);
  gemm_bt<<<dim3(16, 32), 256, 0, stream>>>(kb, WkT, bk, Kh, MROWS, D_MODEL, D_MODEL, 1, 1.0f);
  gemm_bt<<<dim3(16, 32), 256, 0, stream>>>(vb, WvT, bv, Vh, MROWS, D_MODEL, D_MODEL, 1, 1.0f);

  attn_kernel<<<dim3(SEQ/64, BATCH*NHEADS), 256, 0, stream>>>(Qh, Kh, Vh, Oc);

  gemm_bt<<<dim3(16, 32), 256, 0, stream>>>(Oc, WoT, bo, out, MROWS, D_MODEL, D_MODEL, 0, 1.0f);
}

// Round 3
// 368.086 us; speedup vs baseline: 1.2507x; 1.2507x over previous
//
#include <hip/hip_runtime.h>
#include <hip/hip_bf16.h>
#include <stdint.h>

typedef float  f32x4  __attribute__((ext_vector_type(4)));
typedef float  f32x16 __attribute__((ext_vector_type(16)));
typedef short  s16x8  __attribute__((ext_vector_type(8)));

#define D_MODEL 2048
#define NHEADS  16
#define DK      128
#define BATCH   2
#define SEQ     2048
#define MROWS   (BATCH*SEQ)   // 4096

__device__ __forceinline__ unsigned short f2bf(float f) {
  union { float f; unsigned int u; } v; v.f = f;
  unsigned int r = v.u + 0x7FFFu + ((v.u >> 16) & 1u);
  return (unsigned short)(r >> 16);
}

__device__ __forceinline__ unsigned int packbf(float lo, float hi) {
  return (unsigned int)f2bf(lo) | ((unsigned int)f2bf(hi) << 16);
}

__device__ __forceinline__ void async16(const void* g, void* l) {
  __builtin_amdgcn_global_load_lds(
      (const __attribute__((address_space(1))) unsigned int*)g,
      (__attribute__((address_space(3))) unsigned int*)l,
      16, 0, 0);
}

// ---------------- fp32 -> bf16 convert, q/k/v in one launch ----------------
__global__ __launch_bounds__(256) void f2b3_kernel(const float* __restrict__ q,
                                                   const float* __restrict__ k,
                                                   const float* __restrict__ v,
                                                   unsigned short* __restrict__ qb,
                                                   unsigned short* __restrict__ kb,
                                                   unsigned short* __restrict__ vb) {
  const float* s; unsigned short* d;
  switch (blockIdx.y) {
    case 0:  s = q; d = qb; break;
    case 1:  s = k; d = kb; break;
    default: s = v; d = vb; break;
  }
  int i = blockIdx.x * 256 + threadIdx.x;
  const float4* s4 = (const float4*)s;
  float4 a = s4[2*i];
  float4 b = s4[2*i+1];
  s16x8 o;
  o[0] = (short)f2bf(a.x); o[1] = (short)f2bf(a.y);
  o[2] = (short)f2bf(a.z); o[3] = (short)f2bf(a.w);
  o[4] = (short)f2bf(b.x); o[5] = (short)f2bf(b.y);
  o[6] = (short)f2bf(b.z); o[7] = (short)f2bf(b.w);
  *(s16x8*)(d + 8*(size_t)i) = o;
}

// ---------------- weight transpose + convert: Wt[n][k] = bf16(W[k][n]) ----------------
__global__ __launch_bounds__(256) void wtrans_kernel(const float* __restrict__ Wq,
                                                     const float* __restrict__ Wk,
                                                     const float* __restrict__ Wv,
                                                     const float* __restrict__ Wo,
                                                     unsigned short* __restrict__ WqT,
                                                     unsigned short* __restrict__ WkT,
                                                     unsigned short* __restrict__ WvT,
                                                     unsigned short* __restrict__ WoT) {
  const float* W; unsigned short* Wt;
  switch (blockIdx.z) {
    case 0:  W = Wq; Wt = WqT; break;
    case 1:  W = Wk; Wt = WkT; break;
    case 2:  W = Wv; Wt = WvT; break;
    default: W = Wo; Wt = WoT; break;
  }
  __shared__ float tl[32][33];
  int x = threadIdx.x, y = threadIdx.y;
  int n0 = blockIdx.x * 32, k0 = blockIdx.y * 32;
  #pragma unroll
  for (int j = 0; j < 32; j += 8)
    tl[y + j][x] = W[(size_t)(k0 + y + j) * D_MODEL + n0 + x];
  __syncthreads();
  #pragma unroll
  for (int j = 0; j < 32; j += 8)
    Wt[(size_t)(n0 + y + j) * D_MODEL + k0 + x] = f2bf(tl[x][y + j]);
}

// ---------------- GEMM: C[m][n] = sum_k A[m][k]*Bt[n][k] + bias[n]  (m97 structure) ----------------
__global__ __launch_bounds__(256) void gemm_bt(const unsigned short* __restrict__ A,
                                               const unsigned short* __restrict__ Bt,
                                               const float* __restrict__ bias,
                                               void* __restrict__ Cout,
                                               int M, int N, int K,
                                               int mode, float scale) {
  __shared__ unsigned short As[128*32];
  __shared__ unsigned short Bs[128*32];
  const int t  = threadIdx.x;
  const int l  = t & 63, w = t >> 6;
  const int wr = w >> 1, wc = w & 1;
  const int m0 = blockIdx.y * 128, n0 = blockIdx.x * 128;
  const int lr = l & 15, lg = l >> 4;

  f32x4 acc[4][4] = {};

  for (int k0 = 0; k0 < K; k0 += 32) {
    __syncthreads();
    #pragma unroll
    for (int i = 0; i < 2; ++i) {
      int c    = t + 256*i;
      int row  = c >> 2;
      int col8 = (c & 3) * 8;
      async16(A  + (size_t)(m0 + row)*K + k0 + col8, (char*)As + c*16);
      async16(Bt + (size_t)(n0 + row)*K + k0 + col8, (char*)Bs + c*16);
    }
    asm volatile("s_waitcnt vmcnt(0)" ::: "memory");
    __syncthreads();

    s16x8 af[4], bfr[4];
    #pragma unroll
    for (int m = 0; m < 4; ++m)
      af[m] = *(const s16x8*)&As[(wr*64 + m*16 + lr)*32 + 8*lg];
    #pragma unroll
    for (int n = 0; n < 4; ++n)
      bfr[n] = *(const s16x8*)&Bs[(wc*64 + n*16 + lr)*32 + 8*lg];
    #pragma unroll
    for (int m = 0; m < 4; ++m)
      #pragma unroll
      for (int n = 0; n < 4; ++n)
        acc[m][n] = __builtin_amdgcn_mfma_f32_16x16x32_bf16(af[m], bfr[n], acc[m][n], 0, 0, 0);
  }

  if (mode == 0) {
    float* C = (float*)Cout;
    #pragma unroll
    for (int n = 0; n < 4; ++n) {
      int col = n0 + wc*64 + n*16 + lr;
      float bv = bias[col];
      #pragma unroll
      for (int m = 0; m < 4; ++m) {
        int rowb = m0 + wr*64 + m*16 + lg*4;
        #pragma unroll
        for (int r = 0; r < 4; ++r)
          C[(size_t)(rowb + r)*N + col] = (acc[m][n][r] + bv) * scale;
      }
    }
  } else {
    unsigned short* C = (unsigned short*)Cout;
    #pragma unroll
    for (int n = 0; n < 4; ++n) {
      int col = n0 + wc*64 + n*16 + lr;
      float bv = bias[col];
      int h = col >> 7, dkk = col & 127;
      #pragma unroll
      for (int m = 0; m < 4; ++m) {
        int rowb = m0 + wr*64 + m*16 + lg*4;
        #pragma unroll
        for (int r = 0; r < 4; ++r) {
          int row = rowb + r;
          int b = row >> 11, s = row & 2047;
          C[((size_t)((b*NHEADS + h)*SEQ + s))*DK + dkk] = f2bf((acc[m][n][r] + bv) * scale);
        }
      }
    }
  }
}

// ---------------- flash attention, swapped-QK^T 32x32 structure ----------------
// 4 waves x 32 q-rows = 128 q-rows/block. KVBLK=64.
// S^T = mfma(K, Q^T): lane holds S[kv regs][q = lane&31] -> in-register softmax.
// O^T = mfma(V^T, P^T): acc C[dv][q] lane-aligned with softmax state.
// P redistribution via __shfl_xor(32) + select (no permlane/cvt_pk asm).
__global__ __launch_bounds__(256, 2) void attn_kernel(const unsigned short* __restrict__ Q,
                                                      const unsigned short* __restrict__ K,
                                                      const unsigned short* __restrict__ V,
                                                      unsigned short* __restrict__ O) {
  __shared__ char lds[64*256 + 128*144];           // K 16KB + Vt 18KB (reused as O-bounce)
  unsigned short* Kl = (unsigned short*)lds;       // [64][128] bf16, XOR-swizzled rows
  unsigned short* Vt = (unsigned short*)(lds + 64*256); // [128 dv][72 kv] bf16 (padded)

  const int t  = threadIdx.x;
  const int l  = t & 63, w = t >> 6;
  const int q_ = l & 31, hi = l >> 5;
  const int bh = blockIdx.y;
  const int b  = bh >> 4, h = bh & 15;
  const int q0 = blockIdx.x * 128;

  const unsigned short* Qp = Q + (size_t)bh * SEQ * DK;
  const unsigned short* Kp = K + (size_t)bh * SEQ * DK;
  const unsigned short* Vp = V + (size_t)bh * SEQ * DK;

  // Q fragments for B-operand: lane holds Q[qrow][kk*16 + hi*8 .. +8]
  const int qrow = q0 + w*32 + q_;
  s16x8 aq[8];
  #pragma unroll
  for (int kk = 0; kk < 8; ++kk)
    aq[kk] = *(const s16x8*)(Qp + (size_t)qrow*DK + kk*16 + hi*8);

  f32x16 accO[4] = {};                 // C[dv = sub*32 + reg-map][q = q_]
  float m = -INFINITY, L = 0.f;

  const int vp_ = t & 31;
  const int vd0 = (t >> 5) * 8;

  for (int kv0 = 0; kv0 < SEQ; kv0 += 64) {
    __syncthreads();
    // stage K: linear LDS dest, inverse-swizzled global source
    #pragma unroll
    for (int i = 0; i < 4; ++i) {
      int c   = t + 256*i;                 // 1024 chunks of 16B
      int row = c >> 4;
      int sb  = ((c & 15) << 4) ^ ((row & 15) << 4);
      async16((const char*)(Kp + (size_t)(kv0 + row)*DK) + sb, (char*)Kl + c*16);
    }
    // stage V transposed: Vt[dv][kv], kv pairs packed as b32
    #pragma unroll
    for (int rep = 0; rep < 2; ++rep) {
      int dvb = vd0 + rep*64;
      s16x8 va = *(const s16x8*)(Vp + (size_t)(kv0 + 2*vp_    )*DK + dvb);
      s16x8 vb = *(const s16x8*)(Vp + (size_t)(kv0 + 2*vp_ + 1)*DK + dvb);
      #pragma unroll
      for (int j = 0; j < 8; ++j) {
        unsigned int pk = (unsigned int)(unsigned short)va[j]
                        | ((unsigned int)(unsigned short)vb[j] << 16);
        *(unsigned int*)&Vt[(dvb + j)*72 + 2*vp_] = pk;
      }
    }
    asm volatile("s_waitcnt vmcnt(0) lgkmcnt(0)" ::: "memory");
    __syncthreads();

    // S^T[kv][q]: two 32-kv subtiles, 8 dk-slices each
    f32x16 S0 = {}, S1 = {};
    #pragma unroll
    for (int t2 = 0; t2 < 2; ++t2) {
      int krow = t2*32 + q_;
      const char* kb = (const char*)Kl + krow*256;
      int swz = (krow & 15) << 4;
      #pragma unroll
      for (int kk = 0; kk < 8; ++kk) {
        s16x8 kf = *(const s16x8*)(kb + ((kk*32 + hi*16) ^ swz));
        if (t2 == 0) S0 = __builtin_amdgcn_mfma_f32_32x32x16_bf16(kf, aq[kk], S0, 0, 0, 0);
        else         S1 = __builtin_amdgcn_mfma_f32_32x32x16_bf16(kf, aq[kk], S1, 0, 0, 0);
      }
    }

    // ---- in-register online softmax (lane owns q = q_; partner lane l^32 has other half) ----
    f32x16 mx;
    #pragma unroll
    for (int r = 0; r < 16; ++r) mx[r] = fmaxf(S0[r], S1[r]);
    float m8[8];
    #pragma unroll
    for (int r = 0; r < 8; ++r) m8[r] = fmaxf(mx[r], mx[r+8]);
    float m4a = fmaxf(m8[0], m8[4]), m4b = fmaxf(m8[1], m8[5]);
    float m4c = fmaxf(m8[2], m8[6]), m4d = fmaxf(m8[3], m8[7]);
    float pmax = fmaxf(fmaxf(m4a, m4b), fmaxf(m4c, m4d));
    pmax = fmaxf(pmax, __shfl_xor(pmax, 32, 64));
    float mnew = fmaxf(m, pmax);
    float corr = __expf(m - mnew);
    m = mnew;
    float rs0 = 0.f, rs1 = 0.f, rs2 = 0.f, rs3 = 0.f;
    #pragma unroll
    for (int r = 0; r < 4; ++r) {
      float a0 = __expf(S0[r]    - mnew); S0[r]    = a0; rs0 += a0;
      float a1 = __expf(S0[r+4]  - mnew); S0[r+4]  = a1; rs1 += a1;
      float a2 = __expf(S0[r+8]  - mnew); S0[r+8]  = a2; rs2 += a2;
      float a3 = __expf(S0[r+12] - mnew); S0[r+12] = a3; rs3 += a3;
      float b0 = __expf(S1[r]    - mnew); S1[r]    = b0; rs0 += b0;
      float b1 = __expf(S1[r+4]  - mnew); S1[r+4]  = b1; rs1 += b1;
      float b2 = __expf(S1[r+8]  - mnew); S1[r+8]  = b2; rs2 += b2;
      float b3 = __expf(S1[r+12] - mnew); S1[r+12] = b3; rs3 += b3;
    }
    float rs = (rs0 + rs1) + (rs2 + rs3);
    rs += __shfl_xor(rs, 32, 64);
    L = L*corr + rs;
    #pragma unroll
    for (int sub = 0; sub < 4; ++sub)
      #pragma unroll
      for (int r = 0; r < 16; ++r) accO[sub][r] *= corr;

    // ---- P -> bf16 B-fragments via shfl_xor(32) + select ----
    // B-frag chunk kk (kv kk*16..+15): lane needs P[q_][kv = kk*16 + 8*hi + j], j=0..7.
    // Lane's own regs hold kv crow(r,hi)=(r&3)+8*(r>>2)+4*hi; partner (l^32) holds same q.
    s16x8 PB[4];
    #pragma unroll
    for (int t2 = 0; t2 < 2; ++t2) {
      #pragma unroll
      for (int half = 0; half < 2; ++half) {
        int bse = half*8;
        unsigned int pkA01, pkA23, pkB01, pkB23;
        if (t2 == 0) {
          pkA01 = packbf(S0[bse+0], S0[bse+1]);
          pkA23 = packbf(S0[bse+2], S0[bse+3]);
          pkB01 = packbf(S0[bse+4], S0[bse+5]);
          pkB23 = packbf(S0[bse+6], S0[bse+7]);
        } else {
          pkA01 = packbf(S1[bse+0], S1[bse+1]);
          pkA23 = packbf(S1[bse+2], S1[bse+3]);
          pkB01 = packbf(S1[bse+4], S1[bse+5]);
          pkB23 = packbf(S1[bse+6], S1[bse+7]);
        }
        unsigned int xA01 = __shfl_xor(pkA01, 32, 64);
        unsigned int xA23 = __shfl_xor(pkA23, 32, 64);
        unsigned int xB01 = __shfl_xor(pkB01, 32, 64);
        unsigned int xB23 = __shfl_xor(pkB23, 32, 64);
        union { unsigned int u[4]; s16x8 v; } f;
        f.u[0] = hi ? xB01 : pkA01;   // k = 8hi+{0,1}
        f.u[1] = hi ? xB23 : pkA23;   // k = 8hi+{2,3}
        f.u[2] = hi ? pkB01 : xA01;   // k = 8hi+{4,5}
        f.u[3] = hi ? pkB23 : xA23;   // k = 8hi+{6,7}
        PB[t2*2 + half] = f.v;
      }
    }

    // ---- O^T += V^T P^T : C[dv][q] ----
    #pragma unroll
    for (int sub = 0; sub < 4; ++sub) {
      const char* vb2 = (const char*)Vt + (size_t)(sub*32 + q_)*144 + hi*16;
      #pragma unroll
      for (int kk = 0; kk < 4; ++kk) {
        s16x8 vf = *(const s16x8*)(vb2 + kk*32);
        accO[sub] = __builtin_amdgcn_mfma_f32_32x32x16_bf16(vf, PB[kk], accO[sub], 0, 0, 0);
      }
    }
  }

  // ---- epilogue: per-wave LDS bounce to coalesce [q][dv] stores ----
  __syncthreads();   // all waves done reading K/V before overwrite
  unsigned short* Ob = (unsigned short*)lds + (size_t)w*4096;   // 8KB/wave
  float inv = 1.0f / L;
  #pragma unroll
  for (int sub = 0; sub < 4; ++sub)
    #pragma unroll
    for (int j = 0; j < 8; ++j) {
      unsigned int pw = packbf(accO[sub][2*j]*inv, accO[sub][2*j+1]*inv);
      int dv = sub*32 + (j&1)*2 + ((j>>1)*8) + 4*hi;
      *(unsigned int*)((char*)Ob + q_*256 + ((dv*2) ^ ((q_ & 15) << 4))) = pw;
    }
  asm volatile("s_waitcnt lgkmcnt(0)" ::: "memory");
  size_t gbase = ((size_t)(b*SEQ + q0 + w*32 + q_))*D_MODEL + h*DK;
  #pragma unroll
  for (int p = 0; p < 8; ++p) {
    int chunk = hi + 2*p;
    s16x8 ov = *(const s16x8*)((char*)Ob + q_*256 + ((chunk*16) ^ ((q_ & 15) << 4)));
    *(s16x8*)(O + gbase + chunk*8) = ov;
  }
}

extern "C" void kernel_launch(void* const* d_in, const int* in_sizes, int n_in,
                              void* d_out, int out_size, void* d_ws, size_t ws_size,
                              hipStream_t stream) {
  const float* q  = (const float*)d_in[0];
  const float* k  = (const float*)d_in[1];
  const float* v  = (const float*)d_in[2];
  const float* Wq = (const float*)d_in[3];
  const float* bq = (const float*)d_in[4];
  const float* Wk = (const float*)d_in[5];
  const float* bk = (const float*)d_in[6];
  const float* Wv = (const float*)d_in[7];
  const float* bv = (const float*)d_in[8];
  const float* Wo = (const float*)d_in[9];
  const float* bo = (const float*)d_in[10];
  float* out = (float*)d_out;

  char* ws = (char*)d_ws;
  const size_t SZT = (size_t)MROWS * D_MODEL * 2;
  const size_t SZW = (size_t)D_MODEL * D_MODEL * 2;

  unsigned short* qb  = (unsigned short*)(ws);
  unsigned short* kb  = (unsigned short*)(ws + SZT);
  unsigned short* vb  = (unsigned short*)(ws + 2*SZT);
  unsigned short* WqT = (unsigned short*)(ws + 3*SZT);
  unsigned short* WkT = (unsigned short*)(ws + 3*SZT + SZW);
  unsigned short* WvT = (unsigned short*)(ws + 3*SZT + 2*SZW);
  unsigned short* WoT = (unsigned short*)(ws + 3*SZT + 3*SZW);
  unsigned short* Qh  = (unsigned short*)(ws + 3*SZT + 4*SZW);
  unsigned short* Kh  = (unsigned short*)(ws + 4*SZT + 4*SZW);
  unsigned short* Vh  = (unsigned short*)(ws + 5*SZT + 4*SZW);
  unsigned short* Oc  = qb;   // qb dead after Q projection

  const int n8 = MROWS * D_MODEL / 8;
  f2b3_kernel<<<dim3(n8/256, 3), 256, 0, stream>>>(q, k, v, qb, kb, vb);
  wtrans_kernel<<<dim3(64, 64, 4), dim3(32, 8), 0, stream>>>(Wq, Wk, Wv, Wo, WqT, WkT, WvT, WoT);

  const float qscale = 0.08838834764831845f;  // 1/sqrt(128) folded into Q projection
  gemm_bt<<<dim3(16, 32), 256, 0, stream>>>(qb, WqT, bq, Qh, MROWS, D_MODEL, D_MODEL, 1, qscale);
  gemm_bt<<<dim3(16, 32), 256, 0, stream>>>(kb, WkT, bk, Kh, MROWS, D_MODEL, D_MODEL, 1, 1.0f);
  gemm_bt<<<dim3(16, 32), 256, 0, stream>>>(vb, WvT, bv, Vh, MROWS, D_MODEL, D_MODEL, 1, 1.0f);

  attn_kernel<<<dim3(SEQ/128, BATCH*NHEADS), 256, 0, stream>>>(Qh, Kh, Vh, Oc);

  gemm_bt<<<dim3(16, 32), 256, 0, stream>>>(Oc, WoT, bo, out, MROWS, D_MODEL, D_MODEL, 0, 1.0f);
}